// Round 7
// baseline (330.664 us; speedup 1.0000x reference)
//
#include <hip/hip_runtime.h>
#include <hip/hip_bf16.h>
#include <cstdint>
#include <cstddef>

// Problem dims (fixed by the reference)
#define M_DIM 16384
#define IN_F  1024
#define OUT_F 2048
#define K_CAT 2048            // concatenated K = 2*IN_F
#define NT    (K_CAT / 32)    // 64 K-tiles of BK=32

typedef float f32x16 __attribute__((ext_vector_type(16)));
typedef short short8 __attribute__((ext_vector_type(8)));   // 8 bf16 in 4 VGPRs

// async global->LDS, 16B per lane (global_load_lds_dwordx4)
__device__ __forceinline__ void gld_lds16(const void* gptr, void* lptr) {
    __builtin_amdgcn_global_load_lds(
        (const __attribute__((address_space(1))) uint32_t*)gptr,
        (__attribute__((address_space(3))) uint32_t*)lptr,
        16 /*bytes*/, 0 /*offset*/, 0 /*aux*/);
}

// ---------------------------------------------------------------------------
// prep_z: A = [bf16(z*z) | bf16(z)] as (M, 2048) row-major. 8 floats/thread.
// ---------------------------------------------------------------------------
__global__ __launch_bounds__(256) void prep_z_kernel(const float* __restrict__ z,
                                                     __hip_bfloat16* __restrict__ A) {
    const int idx = blockIdx.x * 256 + threadIdx.x;   // 0 .. M*IN_F/8-1
    const int m  = idx >> 7;          // / (IN_F/8)
    const int c8 = (idx & 127) * 8;
    const float4 v0 = ((const float4*)z)[idx * 2];
    const float4 v1 = ((const float4*)z)[idx * 2 + 1];
    const float x[8] = {v0.x, v0.y, v0.z, v0.w, v1.x, v1.y, v1.z, v1.w};
    __hip_bfloat16 q[8], r[8];
#pragma unroll
    for (int j = 0; j < 8; ++j) {
        q[j] = __float2bfloat16(x[j] * x[j]);
        r[j] = __float2bfloat16(x[j]);
    }
    __hip_bfloat16* rowp = A + (size_t)m * K_CAT;
    *(uint4*)&rowp[c8]        = *(uint4*)q;   // z^2 half
    *(uint4*)&rowp[IN_F + c8] = *(uint4*)r;   // z half
}

// ---------------------------------------------------------------------------
// prep_b: B[k,:] = [bf16(-d) | bf16(2*d*mean)]  (OUT_F x 2048, B^T layout)
//         mcm[k] = sum_i d*mean^2 ; ts[k] = tanh(scale[k])
// ---------------------------------------------------------------------------
__global__ __launch_bounds__(256) void prep_b_kernel(const float* __restrict__ diag,
                                                     const float* __restrict__ mean,
                                                     const float* __restrict__ scale,
                                                     __hip_bfloat16* __restrict__ B,
                                                     float* __restrict__ mcm,
                                                     float* __restrict__ ts) {
    const int k = blockIdx.x;
    const int t = threadIdx.x;
    const float4 dp = ((const float4*)(diag + (size_t)k * IN_F))[t];
    const float4 mp = ((const float4*)(mean + (size_t)k * IN_F))[t];
    const float dx[4] = {dp.x, dp.y, dp.z, dp.w};
    const float mx[4] = {mp.x, mp.y, mp.z, mp.w};
    __hip_bfloat16 nb[4], pb[4];
    float acc = 0.f;
#pragma unroll
    for (int j = 0; j < 4; ++j) {
        const float d = 0.1f + 0.9f / (1.f + __expf(-dx[j]));  // sigmoid clamp
        nb[j] = __float2bfloat16(-d);
        pb[j] = __float2bfloat16(2.f * d * mx[j]);
        acc += d * mx[j] * mx[j];
    }
    __hip_bfloat16* rowp = B + (size_t)k * K_CAT;
    *(uint2*)&rowp[t * 4]        = *(uint2*)nb;
    *(uint2*)&rowp[IN_F + t * 4] = *(uint2*)pb;
#pragma unroll
    for (int off = 32; off > 0; off >>= 1) acc += __shfl_down(acc, off);
    __shared__ float red[4];
    if ((t & 63) == 0) red[t >> 6] = acc;
    __syncthreads();
    if (t == 0) {
        mcm[k] = red[0] + red[1] + red[2] + red[3];
        ts[k]  = tanhf(scale[k]);
    }
}

// ---------------------------------------------------------------------------
// gemm_exp: out[m,n] = ts[n] * exp( A(m,:)·B(n,:) - mcm[n] )
// BM=BN=256, BK=32, 8 waves (2M x 4N), per-wave 128x64, mfma 32x32x16.
// Register-level A-frag double-buffer: per kt, read B(kt) + A(kt+1);
// lgkmcnt(8) gates only B; the 8 A-next ds_reads drain UNDER the 16 MFMAs.
// Staging soundness: end-of-kt vmcnt(4) => tile kt+2 landed (per wave's own
// share) BEFORE the barrier; barrier => ALL waves' shares landed before
// anyone reads tile kt+2 at iteration kt+1. One barrier per kt.
// k-slot XOR swizzle (both sides: pre-swizzled global source + swizzled
// ds_read offset; LDS dest linear for global_load_lds).
// ---------------------------------------------------------------------------
__global__ __launch_bounds__(512, 2) void gemm_exp_kernel(
    const __hip_bfloat16* __restrict__ A,   // M x 2048
    const __hip_bfloat16* __restrict__ B,   // OUT_F x 2048 (B^T)
    const float* __restrict__ mcm,
    const float* __restrict__ ts,
    float* __restrict__ out) {
    __shared__ __align__(16) __hip_bfloat16 smem[4][2][8192];  // 4 bufs x (A,B) x 16KB

    const int t = threadIdx.x;
    // XCD-aware swizzle: nwg=512, 512%8==0 -> simple form is bijective.
    const int wg = ((blockIdx.x & 7) << 6) | (blockIdx.x >> 3);
    const int tn = wg & 7;    // 8 N tiles (consecutive wg share the A panel)
    const int tm = wg >> 3;   // 64 M tiles

    // --- staging: chunk c covers LDS bytes [c*16, c*16+16) ---
    // row = c>>2 (64B rows), LDS 16B-slot u = c&3 holds global k-sub u^((row>>1)&3)
    const int c0 = t, c1 = t + 512;
    const int r0 = c0 >> 2, u0 = c0 & 3;
    const int r1 = c1 >> 2, u1 = c1 & 3;
    const int s0 = u0 ^ ((r0 >> 1) & 3);
    const int s1 = u1 ^ ((r1 >> 1) & 3);
    const __hip_bfloat16* gA0 = A + (size_t)(tm * 256 + r0) * K_CAT + s0 * 8;
    const __hip_bfloat16* gA1 = A + (size_t)(tm * 256 + r1) * K_CAT + s1 * 8;
    const __hip_bfloat16* gB0 = B + (size_t)(tn * 256 + r0) * K_CAT + s0 * 8;
    const __hip_bfloat16* gB1 = B + (size_t)(tn * 256 + r1) * K_CAT + s1 * 8;

#define ISSUE_A(buf_, kt_) do { \
        gld_lds16(gA0 + (kt_) * 32, &smem[buf_][0][c0 * 8]); \
        gld_lds16(gA1 + (kt_) * 32, &smem[buf_][0][c1 * 8]); } while (0)
#define ISSUE_B(buf_, kt_) do { \
        gld_lds16(gB0 + (kt_) * 32, &smem[buf_][1][c0 * 8]); \
        gld_lds16(gB1 + (kt_) * 32, &smem[buf_][1][c1 * 8]); } while (0)

    // --- fragment read offsets (bf16 elements), swizzled k-slot ---
    // mfma_32x32x16: A row = lane&31, k = (lane>>5)*8 + j  (16B per lane)
    const int wid = t >> 6, lane = t & 63;
    const int wmb = (wid >> 2) * 128;   // wave M base within tile (4 frags of 32)
    const int wnb = (wid & 3) * 64;     // wave N base within tile (2 frags of 32)
    const int l31 = lane & 31, lh = lane >> 5;
    int offA[4][2], offB[2][2];
#pragma unroll
    for (int fm = 0; fm < 4; ++fm) {
        const int r = wmb + fm * 32 + l31;
#pragma unroll
        for (int ks = 0; ks < 2; ++ks) {
            const int slot = 2 * ks + lh;
            offA[fm][ks] = r * 32 + (slot ^ ((r >> 1) & 3)) * 8;
        }
    }
#pragma unroll
    for (int fn = 0; fn < 2; ++fn) {
        const int r = wnb + fn * 32 + l31;
#pragma unroll
        for (int ks = 0; ks < 2; ++ks) {
            const int slot = 2 * ks + lh;
            offB[fn][ks] = r * 32 + (slot ^ ((r >> 1) & 3)) * 8;
        }
    }

    f32x16 acc[4][2] = {};
    short8 aE[4][2], aO[4][2];   // A-frag double buffer (even/odd kt)

    // --- prologue: stage tiles 0,1,2; wait own share of tile 0; barrier
    //     (barrier after each wave's vmcnt => ALL shares of tile 0 landed) ---
    ISSUE_A(0, 0); ISSUE_B(0, 0);
    ISSUE_A(1, 1); ISSUE_B(1, 1);
    ISSUE_A(2, 2); ISSUE_B(2, 2);
    asm volatile("s_waitcnt vmcnt(8)" ::: "memory");   // own tile-0 loads landed
    __builtin_amdgcn_s_barrier();
    __builtin_amdgcn_sched_barrier(0);
    // read A-frags of tile 0 into aE
#pragma unroll
    for (int fm = 0; fm < 4; ++fm)
#pragma unroll
        for (int ks = 0; ks < 2; ++ks)
            aE[fm][ks] = *(const short8*)&smem[0][0][offA[fm][ks]];
    asm volatile("s_waitcnt lgkmcnt(0)" ::: "memory");
    __builtin_amdgcn_sched_barrier(0);

    // Per sub-iteration (tile KT_): issue prefetch of KT_+3; read B(KT_) and
    // A(KT_+1); lgkmcnt(8) -> B landed (8 A-next reads drain under MFMA);
    // 16 MFMA on ACUR_; vmcnt(4) -> tile KT_+2 landed; barrier.
#define SUBITER(KT_, ACUR_, ANXT_) do {                                        \
    const int pf_   = ((KT_) + 3 < NT) ? (KT_) + 3 : NT - 1;                   \
    const int pbuf_ = ((KT_) + 3) & 3;                                         \
    ISSUE_A(pbuf_, pf_); ISSUE_B(pbuf_, pf_);                                  \
    __builtin_amdgcn_sched_barrier(0);                                         \
    short8 bc_[2][2];                                                          \
    _Pragma("unroll") for (int fn = 0; fn < 2; ++fn)                           \
        _Pragma("unroll") for (int ks = 0; ks < 2; ++ks)                       \
            bc_[fn][ks] = *(const short8*)&smem[(KT_) & 3][1][offB[fn][ks]];   \
    __builtin_amdgcn_sched_barrier(0);  /* pin B-group before A-group */       \
    _Pragma("unroll") for (int fm = 0; fm < 4; ++fm)                           \
        _Pragma("unroll") for (int ks = 0; ks < 2; ++ks)                       \
            ANXT_[fm][ks] = *(const short8*)&smem[((KT_) + 1) & 3][0][offA[fm][ks]]; \
    __builtin_amdgcn_sched_barrier(0);                                         \
    asm volatile("s_waitcnt lgkmcnt(8)" ::: "memory");  /* B landed */         \
    __builtin_amdgcn_sched_barrier(0);                                         \
    __builtin_amdgcn_s_setprio(1);                                             \
    _Pragma("unroll") for (int ks = 0; ks < 2; ++ks)                           \
        _Pragma("unroll") for (int fm = 0; fm < 4; ++fm)                       \
            _Pragma("unroll") for (int fn = 0; fn < 2; ++fn)                   \
                acc[fm][fn] = __builtin_amdgcn_mfma_f32_32x32x16_bf16(         \
                    ACUR_[fm][ks], bc_[fn][ks], acc[fm][fn], 0, 0, 0);         \
    __builtin_amdgcn_s_setprio(0);                                             \
    __builtin_amdgcn_sched_barrier(0);                                         \
    asm volatile("s_waitcnt vmcnt(4)" ::: "memory");  /* tile KT_+2 landed */  \
    __builtin_amdgcn_s_barrier();                                              \
    __builtin_amdgcn_sched_barrier(0);                                         \
} while (0)

    for (int kt = 0; kt < NT; kt += 2) {
        SUBITER(kt,     aE, aO);
        SUBITER(kt + 1, aO, aE);
    }
#undef SUBITER
#undef ISSUE_A
#undef ISSUE_B

    // --- epilogue: 32x32 C/D layout: col=lane&31, row=(reg&3)+8*(reg>>2)+4*(lane>>5)
#pragma unroll
    for (int fn = 0; fn < 2; ++fn) {
        const int gn = tn * 256 + wnb + fn * 32 + l31;
        const float tsv = ts[gn];
        const float mv  = mcm[gn];
#pragma unroll
        for (int fm = 0; fm < 4; ++fm) {
            const int gm0 = tm * 256 + wmb + fm * 32 + lh * 4;
#pragma unroll
            for (int reg = 0; reg < 16; ++reg) {
                const int row = (reg & 3) + 8 * (reg >> 2);
                out[(size_t)(gm0 + row) * OUT_F + gn] = tsv * __expf(acc[fm][fn][reg] - mv);
            }
        }
    }
}

// ---------------------------------------------------------------------------
extern "C" void kernel_launch(void* const* d_in, const int* in_sizes, int n_in,
                              void* d_out, int out_size, void* d_ws, size_t ws_size,
                              hipStream_t stream) {
    const float* z     = (const float*)d_in[0];   // (16384,1024)
    const float* diag  = (const float*)d_in[1];   // (2048,1024)
    const float* mean  = (const float*)d_in[2];   // (2048,1024,1)
    const float* scale = (const float*)d_in[3];   // (2048,)
    float* out = (float*)d_out;                   // (16384,2048)

    char* ws = (char*)d_ws;
    const size_t A_BYTES = (size_t)M_DIM * K_CAT * sizeof(__hip_bfloat16);  // 67.1 MB
    const size_t B_BYTES = (size_t)OUT_F * K_CAT * sizeof(__hip_bfloat16);  //  8.4 MB
    __hip_bfloat16* Abuf = (__hip_bfloat16*)ws;
    __hip_bfloat16* Bbuf = (__hip_bfloat16*)(ws + A_BYTES);
    float* mcm = (float*)(ws + A_BYTES + B_BYTES);
    float* ts  = (float*)(ws + A_BYTES + B_BYTES + 8192);

    prep_z_kernel<<<(M_DIM * IN_F / 8) / 256, 256, 0, stream>>>(z, Abuf);
    prep_b_kernel<<<OUT_F, 256, 0, stream>>>(diag, mean, scale, Bbuf, mcm, ts);
    gemm_exp_kernel<<<(M_DIM / 256) * (OUT_F / 256), 512, 0, stream>>>(
        Abuf, Bbuf, mcm, ts, out);
}

// Round 8
// 320.545 us; speedup vs baseline: 1.0316x; 1.0316x over previous
//
#include <hip/hip_runtime.h>
#include <hip/hip_bf16.h>
#include <cstdint>
#include <cstddef>

// Problem dims (fixed by the reference)
#define M_DIM 16384
#define IN_F  1024
#define OUT_F 2048
#define K_CAT 2048            // concatenated K = 2*IN_F
#define NT    (K_CAT / 32)    // 64 K-tiles of BK=32

typedef float f32x4 __attribute__((ext_vector_type(4)));
typedef short short8 __attribute__((ext_vector_type(8)));   // 8 bf16 in 4 VGPRs

// async global->LDS, 16B per lane (global_load_lds_dwordx4)
__device__ __forceinline__ void gld_lds16(const void* gptr, void* lptr) {
    __builtin_amdgcn_global_load_lds(
        (const __attribute__((address_space(1))) uint32_t*)gptr,
        (__attribute__((address_space(3))) uint32_t*)lptr,
        16 /*bytes*/, 0 /*offset*/, 0 /*aux*/);
}

// ---------------------------------------------------------------------------
// prep_z: A = [bf16(z*z) | bf16(z)] as (M, 2048) row-major. 8 floats/thread.
// ---------------------------------------------------------------------------
__global__ __launch_bounds__(256) void prep_z_kernel(const float* __restrict__ z,
                                                     __hip_bfloat16* __restrict__ A) {
    const int idx = blockIdx.x * 256 + threadIdx.x;   // 0 .. M*IN_F/8-1
    const int m  = idx >> 7;          // / (IN_F/8)
    const int c8 = (idx & 127) * 8;
    const float4 v0 = ((const float4*)z)[idx * 2];
    const float4 v1 = ((const float4*)z)[idx * 2 + 1];
    const float x[8] = {v0.x, v0.y, v0.z, v0.w, v1.x, v1.y, v1.z, v1.w};
    __hip_bfloat16 q[8], r[8];
#pragma unroll
    for (int j = 0; j < 8; ++j) {
        q[j] = __float2bfloat16(x[j] * x[j]);
        r[j] = __float2bfloat16(x[j]);
    }
    __hip_bfloat16* rowp = A + (size_t)m * K_CAT;
    *(uint4*)&rowp[c8]        = *(uint4*)q;   // z^2 half
    *(uint4*)&rowp[IN_F + c8] = *(uint4*)r;   // z half
}

// ---------------------------------------------------------------------------
// prep_b: B[k,:] = [bf16(-d) | bf16(2*d*mean)]  (OUT_F x 2048, B^T layout)
//         mcm[k] = sum_i d*mean^2 ; ts[k] = tanh(scale[k])
// ---------------------------------------------------------------------------
__global__ __launch_bounds__(256) void prep_b_kernel(const float* __restrict__ diag,
                                                     const float* __restrict__ mean,
                                                     const float* __restrict__ scale,
                                                     __hip_bfloat16* __restrict__ B,
                                                     float* __restrict__ mcm,
                                                     float* __restrict__ ts) {
    const int k = blockIdx.x;
    const int t = threadIdx.x;
    const float4 dp = ((const float4*)(diag + (size_t)k * IN_F))[t];
    const float4 mp = ((const float4*)(mean + (size_t)k * IN_F))[t];
    const float dx[4] = {dp.x, dp.y, dp.z, dp.w};
    const float mx[4] = {mp.x, mp.y, mp.z, mp.w};
    __hip_bfloat16 nb[4], pb[4];
    float acc = 0.f;
#pragma unroll
    for (int j = 0; j < 4; ++j) {
        const float d = 0.1f + 0.9f / (1.f + __expf(-dx[j]));  // sigmoid clamp
        nb[j] = __float2bfloat16(-d);
        pb[j] = __float2bfloat16(2.f * d * mx[j]);
        acc += d * mx[j] * mx[j];
    }
    __hip_bfloat16* rowp = B + (size_t)k * K_CAT;
    *(uint2*)&rowp[t * 4]        = *(uint2*)nb;
    *(uint2*)&rowp[IN_F + t * 4] = *(uint2*)pb;
#pragma unroll
    for (int off = 32; off > 0; off >>= 1) acc += __shfl_down(acc, off);
    __shared__ float red[4];
    if ((t & 63) == 0) red[t >> 6] = acc;
    __syncthreads();
    if (t == 0) {
        mcm[k] = red[0] + red[1] + red[2] + red[3];
        ts[k]  = tanhf(scale[k]);
    }
}

// ---------------------------------------------------------------------------
// gemm_exp: out[m,n] = ts[n] * exp( A(m,:)·B(n,:) - mcm[n] )
// BM=BN=256, BK=32, 8 waves (2M x 4N), per-wave 128x64, mfma 16x16x32
// (16-row fragment pattern: measured 0 bank conflicts in R4; the 32x32
//  pattern measured 1.27e7 — reverted).
// Register-level frag double-buffer: at iter kt, MFMA runs on regs(kt)
// (gated LAST iter) while the 12 ds_reads of tile kt+1 drain underneath;
// lgkmcnt(0) AFTER the MFMA block. Counted vmcnt(4): tile kt+2 landed
// before the barrier, tile kt+3's 4 loads stay in flight (never drain to 0).
// One barrier per kt. k-slot XOR swizzle applied on BOTH sides (pre-swizzled
// global source + swizzled ds_read offset; LDS dest linear for gload_lds).
// ---------------------------------------------------------------------------
struct FragSet { short8 a[8]; short8 b[4]; };

__global__ __launch_bounds__(512, 2) void gemm_exp_kernel(
    const __hip_bfloat16* __restrict__ A,   // M x 2048
    const __hip_bfloat16* __restrict__ B,   // OUT_F x 2048 (B^T)
    const float* __restrict__ mcm,
    const float* __restrict__ ts,
    float* __restrict__ out) {
    __shared__ __align__(16) __hip_bfloat16 smem[4][2][8192];  // 4 bufs x (A,B) x 16KB

    const int t = threadIdx.x;
    // XCD-aware swizzle: nwg=512, 512%8==0 -> simple form is bijective.
    const int wg = ((blockIdx.x & 7) << 6) | (blockIdx.x >> 3);
    const int tn = wg & 7;    // 8 N tiles (consecutive wg share the A panel)
    const int tm = wg >> 3;   // 64 M tiles

    // --- staging: chunk c covers LDS bytes [c*16, c*16+16) ---
    // row = c>>2 (64B rows), LDS 16B-slot u = c&3 holds global k-sub u^((row>>1)&3)
    const int c0 = t, c1 = t + 512;
    const int r0 = c0 >> 2, u0 = c0 & 3;
    const int r1 = c1 >> 2, u1 = c1 & 3;
    const int s0 = u0 ^ ((r0 >> 1) & 3);
    const int s1 = u1 ^ ((r1 >> 1) & 3);
    const __hip_bfloat16* gA0 = A + (size_t)(tm * 256 + r0) * K_CAT + s0 * 8;
    const __hip_bfloat16* gA1 = A + (size_t)(tm * 256 + r1) * K_CAT + s1 * 8;
    const __hip_bfloat16* gB0 = B + (size_t)(tn * 256 + r0) * K_CAT + s0 * 8;
    const __hip_bfloat16* gB1 = B + (size_t)(tn * 256 + r1) * K_CAT + s1 * 8;

#define ISSUE_A(buf_, kt_) do { \
        gld_lds16(gA0 + (kt_) * 32, &smem[buf_][0][c0 * 8]); \
        gld_lds16(gA1 + (kt_) * 32, &smem[buf_][0][c1 * 8]); } while (0)
#define ISSUE_B(buf_, kt_) do { \
        gld_lds16(gB0 + (kt_) * 32, &smem[buf_][1][c0 * 8]); \
        gld_lds16(gB1 + (kt_) * 32, &smem[buf_][1][c1 * 8]); } while (0)

    // --- fragment read offsets (bf16 elements), swizzled k-slot ---
    // 16x16x32: row = lane&15 (per 16-row frag), k-quarter = lane>>4.
    // Proven 0-conflict in R4.
    const int wid = t >> 6, lane = t & 63;
    const int wmb = (wid >> 2) * 128;   // wave M base within tile (8 frags of 16)
    const int wnb = (wid & 3) * 64;     // wave N base within tile (4 frags of 16)
    const int l15 = lane & 15, l4 = lane >> 4;
    int offA[8], offB[4];
#pragma unroll
    for (int fm = 0; fm < 8; ++fm) {
        const int r = wmb + fm * 16 + l15;
        offA[fm] = r * 32 + (l4 ^ ((r >> 1) & 3)) * 8;
    }
#pragma unroll
    for (int fn = 0; fn < 4; ++fn) {
        const int r = wnb + fn * 16 + l15;
        offB[fn] = r * 32 + (l4 ^ ((r >> 1) & 3)) * 8;
    }

    f32x4 acc[8][4] = {};
    FragSet fe, fo;   // frag double buffer (even/odd kt)

    // --- prologue: stage tiles 0,1,2; tiles 0 AND 1 landed; read frags(0) ---
    ISSUE_A(0, 0); ISSUE_B(0, 0);
    ISSUE_A(1, 1); ISSUE_B(1, 1);
    ISSUE_A(2, 2); ISSUE_B(2, 2);
    asm volatile("s_waitcnt vmcnt(4)" ::: "memory");   // tiles 0,1 landed (own share)
    __builtin_amdgcn_s_barrier();                      // -> all waves' shares landed
    __builtin_amdgcn_sched_barrier(0);
#pragma unroll
    for (int fm = 0; fm < 8; ++fm) fe.a[fm] = *(const short8*)&smem[0][0][offA[fm]];
#pragma unroll
    for (int fn = 0; fn < 4; ++fn) fe.b[fn] = *(const short8*)&smem[0][1][offB[fn]];
    asm volatile("s_waitcnt lgkmcnt(0)" ::: "memory");
    __builtin_amdgcn_sched_barrier(0);

    // Per iter kt: issue tile kt+3; ds_read frags(kt+1) into NXT_; 32 MFMA on
    // CUR_ (no wait — gated last iter); lgkmcnt(0) (NXT_ drained under MFMA);
    // vmcnt(4) (tile kt+2 landed, kt+3 in flight); barrier.
#define SUBITER(KT_, CUR_, NXT_) do {                                          \
    const int pf_   = ((KT_) + 3 < NT) ? (KT_) + 3 : NT - 1;                   \
    const int pbuf_ = ((KT_) + 3) & 3;                                         \
    ISSUE_A(pbuf_, pf_); ISSUE_B(pbuf_, pf_);                                  \
    __builtin_amdgcn_sched_barrier(0);                                         \
    _Pragma("unroll") for (int fm = 0; fm < 8; ++fm)                           \
        NXT_.a[fm] = *(const short8*)&smem[((KT_) + 1) & 3][0][offA[fm]];      \
    _Pragma("unroll") for (int fn = 0; fn < 4; ++fn)                           \
        NXT_.b[fn] = *(const short8*)&smem[((KT_) + 1) & 3][1][offB[fn]];      \
    __builtin_amdgcn_sched_barrier(0);                                         \
    __builtin_amdgcn_s_setprio(1);                                             \
    _Pragma("unroll") for (int fm = 0; fm < 8; ++fm)                           \
        _Pragma("unroll") for (int fn = 0; fn < 4; ++fn)                       \
            acc[fm][fn] = __builtin_amdgcn_mfma_f32_16x16x32_bf16(             \
                CUR_.a[fm], CUR_.b[fn], acc[fm][fn], 0, 0, 0);                 \
    __builtin_amdgcn_s_setprio(0);                                             \
    __builtin_amdgcn_sched_barrier(0);                                         \
    asm volatile("s_waitcnt lgkmcnt(0)" ::: "memory");  /* NXT_ landed */      \
    asm volatile("s_waitcnt vmcnt(4)" ::: "memory");    /* tile KT_+2 landed */\
    __builtin_amdgcn_s_barrier();                                              \
    __builtin_amdgcn_sched_barrier(0);                                         \
} while (0)

    for (int kt = 0; kt < NT; kt += 2) {
        SUBITER(kt,     fe, fo);
        SUBITER(kt + 1, fo, fe);
    }
#undef SUBITER
#undef ISSUE_A
#undef ISSUE_B

    // --- epilogue: C/D layout col=lane&15 (N), row=(lane>>4)*4+reg (M) ---
#pragma unroll
    for (int fn = 0; fn < 4; ++fn) {
        const int gn = tn * 256 + wnb + fn * 16 + l15;
        const float tsv = ts[gn];
        const float mv  = mcm[gn];
#pragma unroll
        for (int fm = 0; fm < 8; ++fm) {
            const int gm0 = tm * 256 + wmb + fm * 16 + l4 * 4;
#pragma unroll
            for (int r = 0; r < 4; ++r)
                out[(size_t)(gm0 + r) * OUT_F + gn] = tsv * __expf(acc[fm][fn][r] - mv);
        }
    }
}

// ---------------------------------------------------------------------------
extern "C" void kernel_launch(void* const* d_in, const int* in_sizes, int n_in,
                              void* d_out, int out_size, void* d_ws, size_t ws_size,
                              hipStream_t stream) {
    const float* z     = (const float*)d_in[0];   // (16384,1024)
    const float* diag  = (const float*)d_in[1];   // (2048,1024)
    const float* mean  = (const float*)d_in[2];   // (2048,1024,1)
    const float* scale = (const float*)d_in[3];   // (2048,)
    float* out = (float*)d_out;                   // (16384,2048)

    char* ws = (char*)d_ws;
    const size_t A_BYTES = (size_t)M_DIM * K_CAT * sizeof(__hip_bfloat16);  // 67.1 MB
    const size_t B_BYTES = (size_t)OUT_F * K_CAT * sizeof(__hip_bfloat16);  //  8.4 MB
    __hip_bfloat16* Abuf = (__hip_bfloat16*)ws;
    __hip_bfloat16* Bbuf = (__hip_bfloat16*)(ws + A_BYTES);
    float* mcm = (float*)(ws + A_BYTES + B_BYTES);
    float* ts  = (float*)(ws + A_BYTES + B_BYTES + 8192);

    prep_z_kernel<<<(M_DIM * IN_F / 8) / 256, 256, 0, stream>>>(z, Abuf);
    prep_b_kernel<<<OUT_F, 256, 0, stream>>>(diag, mean, scale, Bbuf, mcm, ts);
    gemm_exp_kernel<<<(M_DIM / 256) * (OUT_F / 256), 512, 0, stream>>>(
        Abuf, Bbuf, mcm, ts, out);
}